// Round 14
// baseline (203.170 us; speedup 1.0000x reference)
//
#include <hip/hip_runtime.h>
#include <math.h>

// VMD: T = 2^20, K = 3, 50 iterations.
// Round-26: REPLACE THE INVERSE TRANSFORMS WITH A 128-TAP CONVOLUTION.
// Each mode's filter R_k(nu) = 1/(1+alpha*q_k(nu)), q_k = sum of 2-3
// quadratics = ONE quadratic -> Lorentzian -> time kernel decays e^{-2pi w s},
// w >= 1/sqrt(3 alpha) = 0.0129 -> at s=128 down e^{-10.4} ~ 3e-5.
// imf_k = Re(IFFT(R_k fhat)) = sum_s Re(r_k)[s] x[t-s] (circular), Re(r_k)
// EVEN. So inv_A2+inv_B2 (~3073 FFTs, ~70us) -> k_kerbuild (exact discrete
// lag-sums of R_k, same nu grid as reference; ~7us) + k_conv (128-tap
// symmetric circular conv of x; ~14us). passB stops writing fhat (-8MB).
// Forward + moments + solve unchanged from R25 (161.5us, absmax 2^-9).
// Workspace:
//   [8,12MB)  ET = |f_hat|^2 transposed (float)
//   [12MB..)  W f64[1024*4]; omegaF float[4]; kerf float[384]
//   [16,32MB) scratch (passA->passB intermediate)

#define ALPHA_F 2000.0f
#define LAGS 128

static __device__ __forceinline__ int lpad2(int i) { return i + (i >> 4); }
static __device__ __forceinline__ int swzA(int i) { return ((i & 7) << 6) | (i >> 3); }
static __device__ __forceinline__ float frcp(float x) { return __builtin_amdgcn_rcpf(x); }

typedef float v2f __attribute__((ext_vector_type(2)));
static __device__ __forceinline__ v2f sp(float s) { v2f r; r.x = s; r.y = s; return r; }
static __device__ __forceinline__ v2f v2(float a, float b) { v2f r; r.x = a; r.y = b; return r; }
static __device__ __forceinline__ v2f pkfma(v2f a, v2f b, v2f c)
{ return __builtin_elementwise_fma(a, b, c); }
static __device__ __forceinline__ v2f cmul(v2f a, v2f w)
{
  v2f t = a * sp(w.x);
  v2f s = v2(-a.y, a.x);
  return pkfma(s, sp(w.y), t);
}
static __device__ __forceinline__ v2f cmulrr(v2f a, float wr, float wi)
{
  v2f t = a * sp(wr);
  v2f s = v2(-a.y, a.x);
  return pkfma(s, sp(wi), t);
}

#define PADN2 1088

// ---------------- DPP reductions (VALU pipe only) ----------------
template<int CTRL>
static __device__ __forceinline__ float dpp_addf(float v)
{
  int r = __builtin_amdgcn_update_dpp(0, __float_as_int(v), CTRL, 0xf, 0xf, true);
  return v + __int_as_float(r);
}
static __device__ __forceinline__ float wave64_sum(float v)
{
  v = dpp_addf<0x111>(v);
  v = dpp_addf<0x112>(v);
  v = dpp_addf<0x114>(v);
  v = dpp_addf<0x118>(v);
  v = dpp_addf<0x142>(v);
  v = dpp_addf<0x143>(v);   // lane 63 = full sum
  return v;
}
static __device__ __forceinline__ float row4_sum(float v)
{
  v = dpp_addf<0x111>(v);
  v = dpp_addf<0x112>(v);   // lane 3 of each 4-group = 4-group sum
  return v;
}
static __device__ __forceinline__ float rdlane(float v, int l)
{
  return __int_as_float(__builtin_amdgcn_readlane(__float_as_int(v), l));
}

// ---------------- radix-4 butterfly helper ---------------------------------
template<int SIGN>
static __device__ __forceinline__ void bfly4(v2f Y0, v2f Y1, v2f Y2, v2f Y3,
    float w1r, float w1i, float w2r, float w2i, float w3r, float w3i,
    v2f& o0, v2f& o1, v2f& o2, v2f& o3)
{
  v2f y1 = cmulrr(Y1, w1r, w1i), y2 = cmulrr(Y2, w2r, w2i),
      y3 = cmulrr(Y3, w3r, w3i);
  v2f t0 = Y0 + y2, t1 = Y0 - y2, t2 = y1 + y3, t3 = y1 - y3;
  o0 = t0 + t2; o2 = t0 - t2;
  v2f ns3 = v2(t3.y, -t3.x);
  if (SIGN < 0) { o1 = t1 + ns3; o3 = t1 - ns3; }
  else          { o1 = t1 - ns3; o3 = t1 + ns3; }
}
template<int SIGN>
static __device__ __forceinline__ void bfly4_nt(v2f X0, v2f X1, v2f X2, v2f X3,
    v2f& o0, v2f& o1, v2f& o2, v2f& o3)   // twiddle-free (stage 0)
{
  v2f t0 = X0 + X2, t1 = X0 - X2, t2 = X1 + X3, t3 = X1 - X3;
  o0 = t0 + t2; o2 = t0 - t2;
  v2f ns3 = v2(t3.y, -t3.x);
  if (SIGN < 0) { o1 = t1 + ns3; o3 = t1 - ns3; }
  else          { o1 = t1 - ns3; o3 = t1 + ns3; }
}

// ---------------- 1024-point radix-4 Stockham FFT -------------------------
template<int SIGN>   // -1 = forward
static __device__ void fft1024p_reg(v2f X0, v2f X1, v2f X2, v2f X3,
                                    v2f* A, v2f* B)
{
  const int u = threadIdx.x;
  {
    v2f o0, o1, o2, o3;
    bfly4_nt<SIGN>(X0, X1, X2, X3, o0, o1, o2, o3);
    const int base = u << 2;
    B[lpad2(base    )] = o0; B[lpad2(base + 1)] = o1;
    B[lpad2(base + 2)] = o2; B[lpad2(base + 3)] = o3;
    __syncthreads();
  }
#pragma unroll
  for (int st = 1; st < 5; ++st) {
    v2f *in  = (st & 1) ? B : A;
    v2f *out = (st & 1) ? A : B;
    const int quarter = 1 << (2 * st);
    const int p = u & (quarter - 1);
    const int g = u >> (2 * st);

    float sw, cw;
    sincospif((float)(2 * p) * (1.0f / (float)(4 << (2 * st))), &sw, &cw);
    const float w1r = cw, w1i = (SIGN < 0) ? -sw : sw;
    const float w2r = w1r * w1r - w1i * w1i, w2i = 2.0f * w1r * w1i;
    const float w3r = w2r * w1r - w2i * w1i, w3i = w2r * w1i + w2i * w1r;

    v2f o0, o1, o2, o3;
    bfly4<SIGN>(in[lpad2(u)], in[lpad2(u + 256)],
                in[lpad2(u + 512)], in[lpad2(u + 768)],
                w1r, w1i, w2r, w2i, w3r, w3i, o0, o1, o2, o3);

    const int base = (g << (2 * st + 2)) + p;
    out[lpad2(base              )] = o0;
    out[lpad2(base +     quarter)] = o1;
    out[lpad2(base + 2 * quarter)] = o2;
    out[lpad2(base + 3 * quarter)] = o3;
    __syncthreads();
  }
}

// ---------------- forward passA: packed-real, 2 columns per block ----------
__global__ __launch_bounds__(256) void k_fwd_passA(const float* __restrict__ x,
                                                   float2* __restrict__ ws0)
{
  __shared__ __align__(16) v2f A[PADN2], B[PADN2];
  const int p = swzA(blockIdx.x);     // 512 blocks; column pair (2p, 2p+1)
  const int tid = threadIdx.x;
  const int c0 = 2 * p;
  v2f X[4];
#pragma unroll
  for (int q = 0; q < 4; ++q)
    X[q] = ((const v2f*)x)[(size_t)(tid + 256 * q) * 512 + p];
  fft1024p_reg<-1>(X[0], X[1], X[2], X[3], A, B);

  // rows k<=511 via q=0,1; k=512 by one thread. Rows k>512 are dead (R20).
  float sa, ca, sb, cb, ssa, cca, ssb, ccb;
  sincospif((float)(c0 * tid) * (2.0f / 1048576.0f), &sa, &ca);
  sincospif((float)((c0 + 1) * tid) * (2.0f / 1048576.0f), &sb, &cb);
  sincospif((float)c0 * (1.0f / 2048.0f), &ssa, &cca);
  sincospif((float)(c0 + 1) * (1.0f / 2048.0f), &ssb, &ccb);
  v2f E0 = v2(ca, -sa), E1 = v2(cb, -sb);
  const v2f S0 = v2(cca, -ssa), S1 = v2(ccb, -ssb);
#pragma unroll
  for (int q = 0; q < 2; ++q) {
    int k = tid + 256 * q;
    int kk = (1024 - k) & 1023;
    v2f Z = B[lpad2(k)];
    v2f Wv = B[lpad2(kk)];
    float X0r = 0.5f * (Z.x + Wv.x), X0i = 0.5f * (Z.y - Wv.y);
    float X1r = 0.5f * (Z.y + Wv.y), X1i = 0.5f * (Wv.x - Z.x);
    v2f o01 = cmul(v2(X0r, X0i), E0);
    v2f o23 = cmul(v2(X1r, X1i), E1);
    float4 o = make_float4(o01.x, o01.y, o23.x, o23.y);
    ((float4*)ws0)[(size_t)k * 512 + p] = o;
    if (q == 0) { E0 = cmul(E0, S0); E1 = cmul(E1, S1); }
  }
  if (tid == 0) {            // k = 512: Z = Wv = B[512] -> X imag parts = 0
    v2f Z = B[lpad2(512)];
    float s0, c0f, s1, c1f;
    sincospif((float)c0 * (1.0f / 1024.0f), &s0, &c0f);
    sincospif((float)(c0 + 1) * (1.0f / 1024.0f), &s1, &c1f);
    v2f o01 = cmul(v2(Z.x, 0.0f), v2(c0f, -s0));
    v2f o23 = cmul(v2(Z.y, 0.0f), v2(c1f, -s1));
    float4 o = make_float4(o01.x, o01.y, o23.x, o23.y);
    ((float4*)ws0)[(size_t)512 * 512 + p] = o;
  }
}

// ---------------- forward passB: 513 blocks; ET only (fhat dropped) ---------
__global__ __launch_bounds__(256) void k_fwd_passB(const float2* __restrict__ ws0,
                                                   float* __restrict__ ET)
{
  __shared__ __align__(16) v2f A[PADN2], B[PADN2];
  const int b = blockIdx.x;        // k1 in [0,512]
  const int tid = threadIdx.x;
  v2f X[4];
#pragma unroll
  for (int q = 0; q < 4; ++q)
    X[q] = ((const v2f*)ws0)[(size_t)b * 1024 + tid + 256 * q];
  fft1024p_reg<-1>(X[0], X[1], X[2], X[3], A, B);
  const bool mir = (b >= 1) && (b <= 511);
#pragma unroll
  for (int q = 0; q < 4; ++q) {
    int k2 = tid + 256 * q;
    v2f v = B[lpad2(k2)];
    float e = v.x * v.x + v.y * v.y;
    ET[(size_t)k2 * 1024 + b] = e;
    if (mir)   // |F| symmetric: (k1,k2) -> (1024-k1, 1023-k2)
      ET[(size_t)(1023 - k2) * 1024 + (1024 - b)] = e;
  }
}

// ---------------- Lagrange basis on nodes x = {0, 1/3, 2/3, 1} --------------
static __device__ __forceinline__ void lag4(float x, float& l0, float& l1,
                                            float& l2, float& l3)
{
  float m0 = x, m1 = x - (1.0f / 3.0f), m2 = x - (2.0f / 3.0f), m3 = x - 1.0f;
  l0 = -4.5f * m1 * m2 * m3;
  l1 = 13.5f * m0 * m2 * m3;
  l2 = -13.5f * m0 * m1 * m3;
  l3 =  4.5f * m0 * m1 * m2;
}

// ---------------- bin weights from E^T (fully contiguous reads) -------------
__global__ __launch_bounds__(256) void k_moments(const float* __restrict__ ET,
                                                 double* __restrict__ W)
{
  __shared__ double red[4 * 4];
  const int B = blockIdx.x;        // bin
  const int k2 = B ^ 512;
  const int tid = threadIdx.x;
  double a0 = 0, a1 = 0, a2 = 0, a3 = 0;
#pragma unroll
  for (int q = 0; q < 4; ++q) {
    int k1 = tid + 256 * q;
    float e = ET[(size_t)k2 * 1024 + k1];   // contiguous
    float l0, l1, l2, l3;
    lag4((float)k1 * (1.0f / 1024.0f), l0, l1, l2, l3);
    a0 += (double)(e * l0); a1 += (double)(e * l1);
    a2 += (double)(e * l2); a3 += (double)(e * l3);
  }
  const int lane = tid & 63, wv = tid >> 6;       // 4 waves
  double pv[4] = { a0, a1, a2, a3 };
#pragma unroll
  for (int j = 0; j < 4; ++j) {
    double v = pv[j];
    for (int off = 32; off; off >>= 1) v += __shfl_down(v, off, 64);
    if (lane == 0) red[wv * 4 + j] = v;
  }
  __syncthreads();
  if (tid < 4)
    W[B * 4 + tid] = red[tid] + red[4 + tid] + red[8 + tid] + red[12 + tid];
}

// ---------------- the whole solve loop in ONE workgroup ---------------------
// 256 threads (4 waves); thread t owns bins 4t..4t+3 (16 nodes, 8 v2f pairs).
// Epilogue zeroes kerf[384] for k_kerbuild's atomics (stream-ordered).
__global__ __launch_bounds__(256) void k_solve(
    const double* __restrict__ W4, const float* __restrict__ omega_init,
    float* __restrict__ omegaF, float* __restrict__ kerf)
{
  __shared__ float red[2][64];   // [buf][slot*4 + wave], slots 0..5 (24 used)
  const int t = threadIdx.x;
  const int lane = t & 63, wv = t >> 6;    // 4 waves

  float Wsc[16], fsc[16];
#pragma unroll
  for (int e = 0; e < 16; ++e) {
    Wsc[e] = (float)W4[t * 16 + e];
    int bin = 4 * t + (e >> 2);
    fsc[e] = (float)((double)bin / 1024.0 + (double)(e & 3) / 3072.0 - 0.5);
  }
  v2f frA[8], WrA[8], WfA[8];
#pragma unroll
  for (int i = 0; i < 8; ++i) {
    frA[i] = v2(fsc[2 * i], fsc[2 * i + 1]);
    WrA[i] = v2(Wsc[2 * i], Wsc[2 * i + 1]);
    WfA[i] = WrA[i] * frA[i];
  }
  float om0 = omega_init[0], om1 = omega_init[1], om2 = omega_init[2];

#pragma unroll 1
  for (int it = 0; it < 49; ++it) {        // n = 0 .. 48
    float* rb = red[it & 1];
    v2f p0 = sp(0.f), p1 = sp(0.f), p2 = sp(0.f),
        p3 = sp(0.f), p4 = sp(0.f), p5 = sp(0.f);

#pragma unroll
    for (int i = 0; i < 8; ++i) {
      const v2f fv = frA[i];
      v2f a0 = fv - sp(om0), a1 = fv - sp(om1), a2 = fv - sp(om2);
      v2f t0 = sp(ALPHA_F) * a0, t1 = sp(ALPHA_F) * a1, t2 = sp(ALPHA_F) * a2;
      v2f m1 = pkfma(t1, a1, sp(1.0f));        // 1 + a d1
      v2f dA = pkfma(t0, a0, m1);              // 1 + a(d0+d1)
      v2f dC = pkfma(t2, a2, m1);              // 1 + a(d1+d2)
      v2f dB = pkfma(t2, a2, dA);              // 1 + a(d0+d1+d2)
      v2f AB = dA * dB, BC = dB * dC, AC = dA * dC;
      v2f ABC = AB * dC;
      float rr = frcp(ABC.x * ABC.y);          // paired reciprocal
      v2f r = v2(rr * ABC.y, rr * ABC.x);
      v2f v0 = r * BC, v1 = r * AC, v2_ = r * AB;      // = w_k
      v2f g0 = v0 * v0, g1 = v1 * v1, g2 = v2_ * v2_;  // = w_k^2
      p0 = pkfma(WfA[i], g0, p0); p1 = pkfma(WfA[i], g1, p1);
      p2 = pkfma(WfA[i], g2, p2);
      p3 = pkfma(WrA[i], g0, p3); p4 = pkfma(WrA[i], g1, p4);
      p5 = pkfma(WrA[i], g2, p5);
    }

    float q0 = p0.x + p0.y, q1 = p1.x + p1.y, q2 = p2.x + p2.y;
    float q3 = p3.x + p3.y, q4 = p4.x + p4.y, q5 = p5.x + p5.y;

    q0 = wave64_sum(q0); q1 = wave64_sum(q1); q2 = wave64_sum(q2);
    q3 = wave64_sum(q3); q4 = wave64_sum(q4); q5 = wave64_sum(q5);
    if (lane == 63) {
      rb[0 * 4 + wv] = q0; rb[1 * 4 + wv] = q1; rb[2 * 4 + wv] = q2;
      rb[3 * 4 + wv] = q3; rb[4 * 4 + wv] = q4; rb[5 * 4 + wv] = q5;
    }
    __syncthreads();                 // the ONLY barrier in the iteration
    float v1r = red[it & 1][lane];   // slot = lane>>2, idx = lane&3 (lane<24)
    v1r = row4_sum(v1r);             // lanes >=24 hold junk; never selected
    float n0 = rdlane(v1r, 3),  n1 = rdlane(v1r, 7),  n2 = rdlane(v1r, 11);
    float e0 = rdlane(v1r, 15), e1 = rdlane(v1r, 19), e2 = rdlane(v1r, 23);
    float ie01 = frcp(e0 * e1);      // paired reciprocal for om0/om1
    om0 = n0 * (ie01 * e1);
    om1 = n1 * (ie01 * e0);
    om2 = n2 * frcp(e2);
  }

  for (int i = t; i < 384; i += 256) kerf[i] = 0.0f;   // for kerbuild atomics
  if (t == 0) { omegaF[0] = om0; omegaF[1] = om1; omegaF[2] = om2; }
}

// ---------------- kernel build: ker_k[s] = (1/T) sum_nu R_k(nu) cos(2pi nu s)
// 512 blocks x 2048-f chunks. Phase 1: R0/R1/R2 -> LDS. Phase 2: threads
// 0..127 (lag s) run a packed 2-f rotation recurrence (re-seeded every 512 f
// with integer-exact angle reduction mod 2T), accumulate, atomicAdd.
__global__ __launch_bounds__(256) void k_kerbuild(const float* __restrict__ omegaF,
                                                  float* __restrict__ kerf)
{
  __shared__ __align__(16) float Rs[3][2048];
  const int tid = threadIdx.x;
  const int b = blockIdx.x;
  const float om0 = omegaF[0], om1 = omegaF[1], om2 = omegaF[2];
  const int f0 = b * 2048;
#pragma unroll
  for (int q = 0; q < 8; ++q) {
    int idx = q * 256 + tid;
    int fi = f0 + idx;
    float nu = (float)(fi - 524288) * (1.0f / 1048576.0f);   // exact
    float a0 = nu - om0, a1 = nu - om1, a2 = nu - om2;
    float d0 = a0 * a0, d1 = a1 * a1, d2 = a2 * a2;
    float tA = fmaf(ALPHA_F, d0 + d1, 1.0f);
    float tB = fmaf(ALPHA_F, d2, tA);
    float tC = fmaf(ALPHA_F, d1 + d2, 1.0f);
    Rs[0][idx] = frcp(tA);
    Rs[1][idx] = frcp(tB);
    Rs[2][idx] = frcp(tC);
  }
  __syncthreads();
  const int s = tid;
  if (s >= LAGS) return;
  float ws_, wc_;   // packed-advance step: angle/pi = 4s/T (exact arg)
  sincospif((float)(4 * s) * (1.0f / 1048576.0f), &ws_, &wc_);
  v2f acc0 = sp(0.f), acc1 = sp(0.f), acc2 = sp(0.f);
#pragma unroll 1
  for (int quar = 0; quar < 4; ++quar) {
    int ubase = quar * 512;
    v2f cr, ci;
    {
      float cv[2], sv[2];
#pragma unroll
      for (int l = 0; l < 2; ++l) {
        int fi = f0 + ubase + l;
        int m = (2 * s * fi) & 2097151;    // (2 s fi) mod 2T, exact int32
        float arg = (float)m * (1.0f / 1048576.0f);
        float sv_, cv_;
        sincospif(arg, &sv_, &cv_);
        if (s & 1) { sv_ = -sv_; cv_ = -cv_; }   // cos(x - pi s) = (-1)^s cos x
        cv[l] = cv_; sv[l] = sv_;
      }
      cr = v2(cv[0], cv[1]); ci = v2(sv[0], sv[1]);
    }
#pragma unroll 4
    for (int it = 0; it < 256; ++it) {
      int u = ubase + 2 * it;
      v2f r0 = *(const v2f*)&Rs[0][u];
      v2f r1 = *(const v2f*)&Rs[1][u];
      v2f r2 = *(const v2f*)&Rs[2][u];
      acc0 = pkfma(r0, cr, acc0);
      acc1 = pkfma(r1, cr, acc1);
      acc2 = pkfma(r2, cr, acc2);
      v2f ncr = pkfma(ci, sp(-ws_), cr * sp(wc_));
      v2f nci = pkfma(cr, sp(ws_), ci * sp(wc_));
      cr = ncr; ci = nci;
    }
  }
  const float sc = 1.0f / 1048576.0f;
  atomicAdd(&kerf[s],       (acc0.x + acc0.y) * sc);
  atomicAdd(&kerf[128 + s], (acc1.x + acc1.y) * sc);
  atomicAdd(&kerf[256 + s], (acc2.x + acc2.y) * sc);
}

// ---------------- symmetric circular convolution: all 3 IMFs ----------------
// 2048 blocks x 512 outputs; xs halo +-127; modes 0/1 packed.
__global__ __launch_bounds__(256) void k_conv(const float* __restrict__ x,
                                              const float* __restrict__ kerf,
                                              float* __restrict__ out)
{
  __shared__ float xs[766];                // 512 + 2*127
  __shared__ __align__(8) float kp01[2 * LAGS];
  __shared__ float kp2[LAGS];
  const int tid = threadIdx.x;
  const int B = blockIdx.x;
  const int base = B * 512 - 127;
  for (int i = tid; i < 766; i += 256)
    xs[i] = x[(base + i) & 1048575];       // circular (power-of-2 mask)
  if (tid < LAGS) {
    kp01[2 * tid]     = kerf[tid];
    kp01[2 * tid + 1] = kerf[128 + tid];
    kp2[tid]          = kerf[256 + tid];
  }
  __syncthreads();
#pragma unroll
  for (int r = 0; r < 2; ++r) {
    int tl = r * 256 + tid;
    int off = 127 + tl;
    float xc = xs[off];
    v2f a01 = (*(const v2f*)&kp01[0]) * sp(xc);
    float a2 = kp2[0] * xc;
#pragma unroll 4
    for (int s = 1; s < LAGS; ++s) {
      float pa = xs[off - s] + xs[off + s];
      a01 = pkfma(*(const v2f*)&kp01[2 * s], sp(pa), a01);
      a2 = fmaf(kp2[s], pa, a2);
    }
    int t = B * 512 + tl;
    out[t]           = a01.x;   // imf0
    out[1048576 + t] = a01.y;   // imf1
    out[2097152 + t] = a2;      // imf2
  }
}

// ---------------- host launch ----------------
extern "C" void kernel_launch(void* const* d_in, const int* in_sizes, int n_in,
                              void* d_out, int out_size, void* d_ws, size_t ws_size,
                              hipStream_t stream)
{
  (void)in_sizes; (void)n_in; (void)out_size; (void)ws_size;
  const float* x       = (const float*)d_in[0];
  const float* om_init = (const float*)d_in[1];
  float* out = (float*)d_out;

  char* w = (char*)d_ws;
  const size_t MB = 1024ull * 1024ull;
  float*  ET       = (float*)(w + 8 * MB);
  double* W4       = (double*)(w + 12 * MB);            // 4096 doubles (32 KB)
  float*  omegaF   = (float*)(w + 12 * MB + 48 * 1024);
  float*  kerf     = (float*)(w + 12 * MB + 64 * 1024); // 384 floats
  float2* scratch  = (float2*)(w + 16 * MB);

  k_fwd_passA<<<512, 256, 0, stream>>>(x, scratch);
  k_fwd_passB<<<513, 256, 0, stream>>>(scratch, ET);
  k_moments<<<1024, 256, 0, stream>>>(ET, W4);
  k_solve<<<1, 256, 0, stream>>>(W4, om_init, omegaF, kerf);
  k_kerbuild<<<512, 256, 0, stream>>>(omegaF, kerf);
  k_conv<<<2048, 256, 0, stream>>>(x, kerf, out);
}